// Round 13
// baseline (185.608 us; speedup 1.0000x reference)
//
#include <hip/hip_runtime.h>
#include <hip/hip_bf16.h>
#include <math.h>

// ws layout (float slots)
#define OFF_XT   1572864UL   // bf16 x^T (bh, 128, l) token-paired u32
#define OFF_VC   3145728UL   // bf16 vc (b, l, 768)
#define OFF_PART 4767744UL   // fp32 partials: [0..191] V-sum (bh:S1,S2); [192..959] dist (bh,jq:D1,D2)
#define OFF_ACC  4780056UL   // 336
#define OFF_CTR  4780392UL   // 1 uint (k5b6 completion counter)
#define OFF_FCWB 4780396UL   // bf16 fcW cast, 21*768 (8064 u16)
#define OFF_CV   8388608UL   // fp32 dist matrix (bh, i, j) 96*256*256

typedef __attribute__((ext_vector_type(8))) __bf16 bf16x8;
typedef __attribute__((ext_vector_type(4))) float f32x4;
typedef __attribute__((ext_vector_type(8))) unsigned short u16x8;

// ---------------- K12: gather -> LDS tile (+xT) + dist (cv fp32) + BN partials ----------------
// (identical to R12)
__global__ __launch_bounds__(512) void k12_fused(const int* __restrict__ tids,
    const float* __restrict__ TF, const float* __restrict__ DF,
    const float* __restrict__ emb, unsigned short* __restrict__ xT,
    float* __restrict__ part, const float* __restrict__ fcW,
    unsigned short* __restrict__ fcWb, float* __restrict__ acc,
    unsigned int* __restrict__ ctr, float* __restrict__ cvws) {
  int bid = blockIdx.x;
  int xcd = bid & 7, idx = bid >> 3;       // 48 blocks per XCD
  int bh = xcd * 12 + idx % 12;            // same bh->XCD map as k45 (L2 handoff)
  int jq = idx / 12;                       // 0..3: dist col-quarter
  int b = bh / 6, h = bh % 6;
  int tid = threadIdx.x;
  __shared__ unsigned short tile[32768];   // 64 KiB
  __shared__ float ssq[256];               // per-row sumsq (LDS only)
  __shared__ float swd1[8], swd2[8], swv1[8], swv2[8];
  if (jq == 1) {                           // fcW -> bf16 cast, partitioned over 96 blocks
    if (tid < 168) {
      int i2 = bh * 168 + tid;
      fcWb[i2] = __bfloat16_as_ushort(__float2bfloat16(fcW[i2]));
    }
  } else if (jq == 0 && bh == 0) {         // zero acc + k5b6 counter (2 launches ahead)
    if (tid < 336) acc[tid] = 0.0f;
    if (tid == 336) *ctr = 0u;
  }
  int sub = tid & 7, row0 = tid >> 3;      // 8 threads per token row
  int c16 = sub * 16;
  float ts1 = 0.0f, ts2 = 0.0f;            // per-thread V-sum partials
#pragma unroll
  for (int p = 0; p < 4; ++p) {
    int r = p * 64 + row0;
    int tok = b * 256 + r;
    int tv = tids[tok];
    float wgt = fminf(TF[tok], 20.0f) * log1pf(1.0f / DF[tok]);
    const float* er = emb + (size_t)tv * 768 + h * 128 + c16;
    float4 e0 = *(const float4*)er;
    float4 e1 = *(const float4*)(er + 4);
    float4 e2 = *(const float4*)(er + 8);
    float4 e3 = *(const float4*)(er + 12);
    float f[16] = {e0.x, e0.y, e0.z, e0.w, e1.x, e1.y, e1.z, e1.w,
                   e2.x, e2.y, e2.z, e2.w, e3.x, e3.y, e3.z, e3.w};
    u16x8 pk0, pk1;
    float s1 = 0.0f, s2 = 0.0f;
#pragma unroll
    for (int e = 0; e < 8; ++e) {
      __hip_bfloat16 hb = __float2bfloat16(f[e] * wgt);
      float g = __bfloat162float(hb);
      s1 += g; s2 += g * g;
      pk0[e] = __bfloat16_as_ushort(hb);
    }
#pragma unroll
    for (int e = 0; e < 8; ++e) {
      __hip_bfloat16 hb = __float2bfloat16(f[8 + e] * wgt);
      float g = __bfloat162float(hb);
      s1 += g; s2 += g * g;
      pk1[e] = __bfloat16_as_ushort(hb);
    }
    ts1 += s1; ts2 += s2;
    int rx = r & 7;
    *(u16x8*)&tile[r * 128 + (((sub * 2    ) ^ rx) * 8)] = pk0;
    *(u16x8*)&tile[r * 128 + (((sub * 2 + 1) ^ rx) * 8)] = pk1;
    s2 += __shfl_down(s2, 4); s2 += __shfl_down(s2, 2); s2 += __shfl_down(s2, 1);
    if (sub == 0) ssq[r] = s2;             // LDS only — no global round-trip
  }
  __syncthreads();
  // jq==3 block emits the channel-major transpose xT (token-paired u32) from LDS
  if (jq == 3) {
    int ch = tid & 127, q = tid >> 7;          // 4 token-quarters
    int cc = ch >> 3, cs = ch & 7;
    unsigned int* xo = (unsigned int*)xT + ((size_t)bh * 128 + ch) * 128 + q * 32;
#pragma unroll
    for (int g = 0; g < 8; ++g) {
      unsigned int tmp[4];
#pragma unroll
      for (int k = 0; k < 4; ++k) {
        int t0 = q * 64 + (g * 4 + k) * 2;
        unsigned int lo = tile[ t0      * 128 + ((cc ^ ( t0      & 7)) * 8) + cs];
        unsigned int hi = tile[(t0 + 1) * 128 + ((cc ^ ((t0 + 1) & 7)) * 8) + cs];
        tmp[k] = lo | (hi << 16);
      }
      uint4 vv; vv.x = tmp[0]; vv.y = tmp[1]; vv.z = tmp[2]; vv.w = tmp[3];
      *(uint4*)(xo + g * 4) = vv;
    }
  }
  // dist: wave w -> i-tiles {2w,2w+1}, cols [64*jq, 64*jq+64); store cv fp32 + BN partials
  int w = tid >> 6, lane = tid & 63, quad = lane >> 4, l16 = lane & 15;
  int it0 = w * 2;
  bf16x8 a2[2][4];
  float si2[2][4];
#pragma unroll
  for (int ith = 0; ith < 2; ++ith) {
    int ar = (it0 + ith) * 16 + l16, arx = ar & 7;
#pragma unroll
    for (int k0 = 0; k0 < 4; ++k0)
      a2[ith][k0] = *(const bf16x8*)&tile[ar * 128 + (((k0 * 4 + quad) ^ arx) * 8)];
#pragma unroll
    for (int r = 0; r < 4; ++r)
      si2[ith][r] = ssq[(it0 + ith) * 16 + quad * 4 + r];
  }
  float ls1 = 0.0f, ls2 = 0.0f;
#pragma unroll
  for (int jt = 0; jt < 4; ++jt) {
    int jcol = jq * 64 + jt * 16 + l16;
    int jrx = jcol & 7;
    bf16x8 bfr[4];
#pragma unroll
    for (int k0 = 0; k0 < 4; ++k0)
      bfr[k0] = *(const bf16x8*)&tile[jcol * 128 + (((k0 * 4 + quad) ^ jrx) * 8)];
    f32x4 acc0 = {0.0f, 0.0f, 0.0f, 0.0f}, acc1 = {0.0f, 0.0f, 0.0f, 0.0f};
#pragma unroll
    for (int k0 = 0; k0 < 4; ++k0) {
      acc0 = __builtin_amdgcn_mfma_f32_16x16x32_bf16(a2[0][k0], bfr[k0], acc0, 0, 0, 0);
      acc1 = __builtin_amdgcn_mfma_f32_16x16x32_bf16(a2[1][k0], bfr[k0], acc1, 0, 0, 0);
    }
    float sj = ssq[jcol];
#pragma unroll
    for (int r = 0; r < 4; ++r) {
      float cv0 = sqrtf(fmaxf(si2[0][r] + sj - 2.0f * acc0[r], 1e-12f));
      float cv1 = sqrtf(fmaxf(si2[1][r] + sj - 2.0f * acc1[r], 1e-12f));
      cvws[((size_t)bh * 256 + (it0    ) * 16 + quad * 4 + r) * 256 + jcol] = cv0;
      cvws[((size_t)bh * 256 + (it0 + 1) * 16 + quad * 4 + r) * 256 + jcol] = cv1;
      ls1 += cv0 + cv1;
      ls2 += cv0 * cv0 + cv1 * cv1;
    }
  }
#pragma unroll
  for (int off = 32; off >= 1; off >>= 1) {
    ls1 += __shfl_down(ls1, off);
    ls2 += __shfl_down(ls2, off);
    ts1 += __shfl_down(ts1, off);
    ts2 += __shfl_down(ts2, off);
  }
  if (lane == 0) { swd1[w] = ls1; swd2[w] = ls2; swv1[w] = ts1; swv2[w] = ts2; }
  __syncthreads();
  if (tid == 0) {
    float d1 = 0.0f, d2 = 0.0f, v1 = 0.0f, v2 = 0.0f;
#pragma unroll
    for (int i = 0; i < 8; ++i) { d1 += swd1[i]; d2 += swd2[i]; v1 += swv1[i]; v2 += swv2[i]; }
    part[192 + (bh * 4 + jq) * 2 + 0] = d1;
    part[192 + (bh * 4 + jq) * 2 + 1] = d2;
    if (jq == 0) { part[bh * 2] = v1; part[bh * 2 + 1] = v2; }
  }
}

// ---------------- K45: stats + bn+leaky+mask+softmax (cv direct) + AV ----------------
// launch_bounds(256,4): cap VGPR<=128 -> 16 waves/CU (4 blocks) instead of 8 if uncapped >128.
__global__ __launch_bounds__(256, 4) void k45_fused(const float* __restrict__ cvws,
    const unsigned short* __restrict__ xT, const int* __restrict__ tids,
    const float* __restrict__ part, unsigned short* __restrict__ vc16) {
  int bid = blockIdx.x;
  int xcd = bid & 7, idx = bid >> 3;
  int bh = xcd * 12 + idx % 12;            // 96 bh / 8 XCDs = 12 each
  int p = idx / 12;
  int b = bh / 6, h = bh % 6;
  int tid = threadIdx.x, w = tid >> 6, lane = tid & 63;
  int quad = lane >> 4, l16 = lane & 15;
  int I = p * 16;
  __shared__ float svld[256];
  __shared__ unsigned short cot[16][264];  // co tile; reused as vc restage buffer (vt)
  __shared__ float smax[16][4];
  __shared__ float ssum[16][4];
  __shared__ float sstat[4];               // m, rsc, mv, rvs
  svld[tid] = (tids[b * 256 + tid] != 0) ? 1.0f : 0.0f;
  if (w == 0) {                            // finalize BN stats from k12 partials (this h only)
    float c1 = 0.0f, c2 = 0.0f;
    {
      int bb = lane >> 2, jj = lane & 3;   // 16 b x 4 jq = 64 lanes
      c1 = part[192 + ((bb * 6 + h) * 4 + jj) * 2 + 0];
      c2 = part[192 + ((bb * 6 + h) * 4 + jj) * 2 + 1];
    }
    float v1 = 0.0f, v2 = 0.0f;
    if (lane < 16) {
      v1 = part[(lane * 6 + h) * 2 + 0];
      v2 = part[(lane * 6 + h) * 2 + 1];
    }
#pragma unroll
    for (int off = 32; off >= 1; off >>= 1) {
      c1 += __shfl_down(c1, off);
      c2 += __shfl_down(c2, off);
      v1 += __shfl_down(v1, off);
      v2 += __shfl_down(v2, off);
    }
    if (lane == 0) {
      float mean = c1 / 1048576.0f;                    // B*L*L
      float var = c2 / 1048576.0f - mean * mean;
      sstat[0] = mean;
      sstat[1] = rsqrtf(var + 1e-5f);
      float mv = v1 / 524288.0f;                       // B*L*dh
      float vv = v2 / 524288.0f - mv * mv;
      sstat[2] = mv;
      sstat[3] = rsqrtf(vv + 1e-5f);
    }
  }
  __syncthreads();
  float m = sstat[0], rsc = sstat[1];
  float rv[4];
#pragma unroll
  for (int r = 0; r < 4; ++r) rv[r] = svld[I + quad * 4 + r];
  const float* cvb = cvws + ((size_t)bh * 256 + I) * 256;   // this tile's 16 rows
  float y[4][4];
#pragma unroll
  for (int tl = 0; tl < 4; ++tl) {
    int t = w * 4 + tl;
    float cvld = svld[t * 16 + l16];
#pragma unroll
    for (int r = 0; r < 4; ++r) {
      float cv = cvb[(quad * 4 + r) * 256 + t * 16 + l16];  // direct (single-use)
      float yv = (cv - m) * rsc;
      yv = yv >= 0.0f ? yv : 9.0f * yv;
      y[tl][r] = yv * rv[r] * cvld;
    }
  }
#pragma unroll
  for (int r = 0; r < 4; ++r) {
    float mx = fmaxf(fmaxf(y[0][r], y[1][r]), fmaxf(y[2][r], y[3][r]));
#pragma unroll
    for (int off = 1; off <= 8; off <<= 1) mx = fmaxf(mx, __shfl_xor(mx, off));
    if (l16 == 0) smax[quad * 4 + r][w] = mx;
  }
  __syncthreads();
  float gmx[4];
#pragma unroll
  for (int r = 0; r < 4; ++r) {
    int row = quad * 4 + r;
    gmx[r] = fmaxf(fmaxf(smax[row][0], smax[row][1]), fmaxf(smax[row][2], smax[row][3]));
    float s = 0.0f;
#pragma unroll
    for (int tl = 0; tl < 4; ++tl) { y[tl][r] = expf(y[tl][r] - gmx[r]); s += y[tl][r]; }
#pragma unroll
    for (int off = 1; off <= 8; off <<= 1) s += __shfl_xor(s, off);
    if (l16 == 0) ssum[row][w] = s;
  }
  __syncthreads();
#pragma unroll
  for (int r = 0; r < 4; ++r) {
    int row = quad * 4 + r;
    float gs = ssum[row][0] + ssum[row][1] + ssum[row][2] + ssum[row][3];
    float inv = 1.0f / gs;
#pragma unroll
    for (int tl = 0; tl < 4; ++tl)
      cot[row][w * 64 + tl * 16 + l16] =
          __bfloat16_as_ushort(__float2bfloat16(y[tl][r] * inv));
  }
  __syncthreads();
  bf16x8 a2[8];
#pragma unroll
  for (int k0 = 0; k0 < 8; ++k0)
    a2[k0] = *(const bf16x8*)&cot[l16][k0 * 32 + quad * 8];
  __syncthreads();                         // cot fragments now in regs; reuse cot as vt
  const __bf16* xbT = (const __bf16*)xT + (size_t)bh * 128 * 256;
  float mv = sstat[2], rvs = sstat[3];
  float rm = rvs * mv;
#pragma unroll
  for (int jl = 0; jl < 2; ++jl) {
    int ch = (w * 2 + jl) * 16 + l16;
    const __bf16* brow = xbT + (size_t)ch * 256;
    f32x4 vacc = {0.0f, 0.0f, 0.0f, 0.0f};
#pragma unroll
    for (int k0 = 0; k0 < 8; ++k0) {
      bf16x8 bfr = *(const bf16x8*)(brow + k0 * 32 + quad * 8);
      vacc = __builtin_amdgcn_mfma_f32_16x16x32_bf16(a2[k0], bfr, vacc, 0, 0, 0);
    }
#pragma unroll
    for (int r = 0; r < 4; ++r) {
      float ov = rvs * vacc[r] - rm;
      cot[quad * 4 + r][ch] = __bfloat16_as_ushort(__float2bfloat16(ov));   // vt stage
    }
  }
  __syncthreads();
  {                                        // coalesced vc store: 1 u16x8 per thread
    int row = tid >> 4, seg = (tid & 15) * 8;
    u16x8 pkv = *(const u16x8*)&cot[row][seg];
    *(u16x8*)(vc16 + ((size_t)(b * 256 + I + row)) * 768 + h * 128 + seg) = pkv;
  }
}

// ---------------- K5b6: 256 blocks x 1 wave (16 tokens each). MFMA logits + 21-softmax
// + per-class atomics + last-block final 20-softmax. No __syncthreads on hot path. ----------------
__global__ __launch_bounds__(64) void k5b6_lgts(const unsigned short* __restrict__ vc16,
    const unsigned short* __restrict__ fcWb, const float* __restrict__ fcb,
    float* __restrict__ acc, unsigned int* __restrict__ ctr, float* __restrict__ out) {
  int bid = blockIdx.x;
  int xcd = bid & 7, idx = bid >> 3;       // 32 blocks per XCD
  int b = xcd * 2 + (idx & 1);             // matches k45's b->XCD map
  int qa = idx >> 1;                       // 0..15: 16-token group
  int lane = threadIdx.x;
  int quad = lane >> 4, l16 = lane & 15;
  int tok0 = b * 256 + qa * 16;
  int c1c = (l16 < 5) ? (16 + l16) : 20;
  const __bf16* vb = (const __bf16*)vc16;
  const __bf16* w0 = (const __bf16*)fcWb + (size_t)l16 * 768;
  const __bf16* w1 = (const __bf16*)fcWb + (size_t)c1c * 768;
  f32x4 ac0 = {0.0f, 0.0f, 0.0f, 0.0f}, ac1 = {0.0f, 0.0f, 0.0f, 0.0f};
#pragma unroll
  for (int k0 = 0; k0 < 24; ++k0) {
    int ko = k0 * 32 + quad * 8;
    bf16x8 af = *(const bf16x8*)(vb + (size_t)(tok0 + l16) * 768 + ko);
    bf16x8 b0 = *(const bf16x8*)(w0 + ko);
    bf16x8 b1 = *(const bf16x8*)(w1 + ko);
    ac0 = __builtin_amdgcn_mfma_f32_16x16x32_bf16(af, b0, ac0, 0, 0, 0);
    ac1 = __builtin_amdgcn_mfma_f32_16x16x32_bf16(af, b1, ac1, 0, 0, 0);
  }
  float bias0 = fcb[l16];
  float bias1 = (l16 < 5) ? fcb[16 + l16] : 0.0f;
  float p0s = 0.0f, p1s = 0.0f;
#pragma unroll
  for (int r = 0; r < 4; ++r) {
    float lg0 = ac0[r] + bias0;
    float lg1 = (l16 < 5) ? (ac1[r] + bias1) : -1e30f;
    float mx = fmaxf(lg0, lg1);
#pragma unroll
    for (int off = 1; off <= 8; off <<= 1) mx = fmaxf(mx, __shfl_xor(mx, off));
    float e0 = expf(lg0 - mx), e1 = expf(lg1 - mx);
    float s = e0 + e1;
#pragma unroll
    for (int off = 1; off <= 8; off <<= 1) s += __shfl_xor(s, off);
    float inv = 1.0f / s;
    p0s += e0 * inv;
    p1s += e1 * inv;
  }
  p0s += __shfl_xor(p0s, 16); p0s += __shfl_xor(p0s, 32);
  p1s += __shfl_xor(p1s, 16); p1s += __shfl_xor(p1s, 32);
  // lanes of quad 0 hold class sums for classes l16 (0..15); quad 1 l16<5 -> classes 16..20
  if (quad == 0) atomicAdd(&acc[b * 21 + l16], p0s);
  if (quad == 1 && l16 < 5) atomicAdd(&acc[b * 21 + 16 + l16], p1s);
  __builtin_amdgcn_s_waitcnt(0);           // drain atomics before signaling
  __threadfence();
  unsigned int done = 0;
  if (lane == 0) done = atomicAdd(ctr, 1u);
  done = __shfl(done, 0);
  if (done == 255u && lane < 16) {
    float v[20];
    float mx2 = -1e30f;
#pragma unroll
    for (int c = 0; c < 20; ++c) {
      v[c] = atomicAdd(&acc[lane * 21 + c], 0.0f);   // coherent read (XCD-safe)
      mx2 = fmaxf(mx2, v[c]);
    }
    float s2 = 0.0f;
#pragma unroll
    for (int c = 0; c < 20; ++c) { v[c] = expf(v[c] - mx2); s2 += v[c]; }
    float inv2 = 1.0f / s2;
#pragma unroll
    for (int c = 0; c < 20; ++c) out[lane * 20 + c] = v[c] * inv2;
  }
}

extern "C" void kernel_launch(void* const* d_in, const int* in_sizes, int n_in,
                              void* d_out, int out_size, void* d_ws, size_t ws_size,
                              hipStream_t stream) {
  const int*   tids = (const int*)d_in[0];
  const float* TF   = (const float*)d_in[1];
  const float* DF   = (const float*)d_in[2];
  const float* emb  = (const float*)d_in[3];
  const float* fcW  = (const float*)d_in[4];
  const float* fcb  = (const float*)d_in[5];
  // d_in[6]=weiW, d_in[7]=weib: dead code (cw branch is provably all-ones)
  float* out = (float*)d_out;
  float* ws  = (float*)d_ws;
  unsigned short* xT   = (unsigned short*)(ws + OFF_XT);
  unsigned short* vc   = (unsigned short*)(ws + OFF_VC);
  unsigned short* fcWb = (unsigned short*)(ws + OFF_FCWB);
  float* part  = ws + OFF_PART;
  float* acc   = ws + OFF_ACC;
  float* cvws  = ws + OFF_CV;
  unsigned int* ctr = (unsigned int*)(ws + OFF_CTR);

  k12_fused<<<384, 512, 0, stream>>>(tids, TF, DF, emb, xT, part,
                                     fcW, fcWb, acc, ctr, cvws);
  k45_fused<<<1536, 256, 0, stream>>>(cvws, xT, tids, part, vc);
  k5b6_lgts<<<256, 64, 0, stream>>>(vc, fcWb, fcb, acc, ctr, out);
}

// Round 14
// 181.547 us; speedup vs baseline: 1.0224x; 1.0224x over previous
//
#include <hip/hip_runtime.h>
#include <hip/hip_bf16.h>
#include <math.h>

// ws layout (float slots)
#define OFF_XT   1572864UL   // bf16 x^T (bh, 128, l) token-paired u32
#define OFF_VC   3145728UL   // bf16 vc (b, l, 768)
#define OFF_PART 4767744UL   // fp32 partials: [0..191] V-sum (bh:S1,S2); [192..959] dist (bh,jq:D1,D2)
#define OFF_ACC  4780056UL   // 336
#define OFF_CTR  4780392UL   // 1 uint (k5b6 completion counter)
#define OFF_FCWB 4780396UL   // bf16 fcW cast, 21*768 (8064 u16)
#define OFF_CV   8388608UL   // fp32 dist matrix (bh, i, j) 96*256*256

typedef __attribute__((ext_vector_type(8))) __bf16 bf16x8;
typedef __attribute__((ext_vector_type(4))) float f32x4;
typedef __attribute__((ext_vector_type(8))) unsigned short u16x8;

// ---------------- K12: gather -> LDS tile (+xT) + dist (cv fp32) + BN partials ----------------
// (identical to R12)
__global__ __launch_bounds__(512) void k12_fused(const int* __restrict__ tids,
    const float* __restrict__ TF, const float* __restrict__ DF,
    const float* __restrict__ emb, unsigned short* __restrict__ xT,
    float* __restrict__ part, const float* __restrict__ fcW,
    unsigned short* __restrict__ fcWb, float* __restrict__ acc,
    unsigned int* __restrict__ ctr, float* __restrict__ cvws) {
  int bid = blockIdx.x;
  int xcd = bid & 7, idx = bid >> 3;       // 48 blocks per XCD
  int bh = xcd * 12 + idx % 12;            // same bh->XCD map as k45 (L2 handoff)
  int jq = idx / 12;                       // 0..3: dist col-quarter
  int b = bh / 6, h = bh % 6;
  int tid = threadIdx.x;
  __shared__ unsigned short tile[32768];   // 64 KiB
  __shared__ float ssq[256];               // per-row sumsq (LDS only)
  __shared__ float swd1[8], swd2[8], swv1[8], swv2[8];
  if (jq == 1) {                           // fcW -> bf16 cast, partitioned over 96 blocks
    if (tid < 168) {
      int i2 = bh * 168 + tid;
      fcWb[i2] = __bfloat16_as_ushort(__float2bfloat16(fcW[i2]));
    }
  } else if (jq == 0 && bh == 0) {         // zero acc + k5b6 counter (2 launches ahead)
    if (tid < 336) acc[tid] = 0.0f;
    if (tid == 336) *ctr = 0u;
  }
  int sub = tid & 7, row0 = tid >> 3;      // 8 threads per token row
  int c16 = sub * 16;
  float ts1 = 0.0f, ts2 = 0.0f;            // per-thread V-sum partials
#pragma unroll
  for (int p = 0; p < 4; ++p) {
    int r = p * 64 + row0;
    int tok = b * 256 + r;
    int tv = tids[tok];
    float wgt = fminf(TF[tok], 20.0f) * log1pf(1.0f / DF[tok]);
    const float* er = emb + (size_t)tv * 768 + h * 128 + c16;
    float4 e0 = *(const float4*)er;
    float4 e1 = *(const float4*)(er + 4);
    float4 e2 = *(const float4*)(er + 8);
    float4 e3 = *(const float4*)(er + 12);
    float f[16] = {e0.x, e0.y, e0.z, e0.w, e1.x, e1.y, e1.z, e1.w,
                   e2.x, e2.y, e2.z, e2.w, e3.x, e3.y, e3.z, e3.w};
    u16x8 pk0, pk1;
    float s1 = 0.0f, s2 = 0.0f;
#pragma unroll
    for (int e = 0; e < 8; ++e) {
      __hip_bfloat16 hb = __float2bfloat16(f[e] * wgt);
      float g = __bfloat162float(hb);
      s1 += g; s2 += g * g;
      pk0[e] = __bfloat16_as_ushort(hb);
    }
#pragma unroll
    for (int e = 0; e < 8; ++e) {
      __hip_bfloat16 hb = __float2bfloat16(f[8 + e] * wgt);
      float g = __bfloat162float(hb);
      s1 += g; s2 += g * g;
      pk1[e] = __bfloat16_as_ushort(hb);
    }
    ts1 += s1; ts2 += s2;
    int rx = r & 7;
    *(u16x8*)&tile[r * 128 + (((sub * 2    ) ^ rx) * 8)] = pk0;
    *(u16x8*)&tile[r * 128 + (((sub * 2 + 1) ^ rx) * 8)] = pk1;
    s2 += __shfl_down(s2, 4); s2 += __shfl_down(s2, 2); s2 += __shfl_down(s2, 1);
    if (sub == 0) ssq[r] = s2;             // LDS only — no global round-trip
  }
  __syncthreads();
  // jq==3 block emits the channel-major transpose xT (token-paired u32) from LDS
  if (jq == 3) {
    int ch = tid & 127, q = tid >> 7;          // 4 token-quarters
    int cc = ch >> 3, cs = ch & 7;
    unsigned int* xo = (unsigned int*)xT + ((size_t)bh * 128 + ch) * 128 + q * 32;
#pragma unroll
    for (int g = 0; g < 8; ++g) {
      unsigned int tmp[4];
#pragma unroll
      for (int k = 0; k < 4; ++k) {
        int t0 = q * 64 + (g * 4 + k) * 2;
        unsigned int lo = tile[ t0      * 128 + ((cc ^ ( t0      & 7)) * 8) + cs];
        unsigned int hi = tile[(t0 + 1) * 128 + ((cc ^ ((t0 + 1) & 7)) * 8) + cs];
        tmp[k] = lo | (hi << 16);
      }
      uint4 vv; vv.x = tmp[0]; vv.y = tmp[1]; vv.z = tmp[2]; vv.w = tmp[3];
      *(uint4*)(xo + g * 4) = vv;
    }
  }
  // dist: wave w -> i-tiles {2w,2w+1}, cols [64*jq, 64*jq+64); store cv fp32 + BN partials
  int w = tid >> 6, lane = tid & 63, quad = lane >> 4, l16 = lane & 15;
  int it0 = w * 2;
  bf16x8 a2[2][4];
  float si2[2][4];
#pragma unroll
  for (int ith = 0; ith < 2; ++ith) {
    int ar = (it0 + ith) * 16 + l16, arx = ar & 7;
#pragma unroll
    for (int k0 = 0; k0 < 4; ++k0)
      a2[ith][k0] = *(const bf16x8*)&tile[ar * 128 + (((k0 * 4 + quad) ^ arx) * 8)];
#pragma unroll
    for (int r = 0; r < 4; ++r)
      si2[ith][r] = ssq[(it0 + ith) * 16 + quad * 4 + r];
  }
  float ls1 = 0.0f, ls2 = 0.0f;
#pragma unroll
  for (int jt = 0; jt < 4; ++jt) {
    int jcol = jq * 64 + jt * 16 + l16;
    int jrx = jcol & 7;
    bf16x8 bfr[4];
#pragma unroll
    for (int k0 = 0; k0 < 4; ++k0)
      bfr[k0] = *(const bf16x8*)&tile[jcol * 128 + (((k0 * 4 + quad) ^ jrx) * 8)];
    f32x4 acc0 = {0.0f, 0.0f, 0.0f, 0.0f}, acc1 = {0.0f, 0.0f, 0.0f, 0.0f};
#pragma unroll
    for (int k0 = 0; k0 < 4; ++k0) {
      acc0 = __builtin_amdgcn_mfma_f32_16x16x32_bf16(a2[0][k0], bfr[k0], acc0, 0, 0, 0);
      acc1 = __builtin_amdgcn_mfma_f32_16x16x32_bf16(a2[1][k0], bfr[k0], acc1, 0, 0, 0);
    }
    float sj = ssq[jcol];
#pragma unroll
    for (int r = 0; r < 4; ++r) {
      float cv0 = sqrtf(fmaxf(si2[0][r] + sj - 2.0f * acc0[r], 1e-12f));
      float cv1 = sqrtf(fmaxf(si2[1][r] + sj - 2.0f * acc1[r], 1e-12f));
      cvws[((size_t)bh * 256 + (it0    ) * 16 + quad * 4 + r) * 256 + jcol] = cv0;
      cvws[((size_t)bh * 256 + (it0 + 1) * 16 + quad * 4 + r) * 256 + jcol] = cv1;
      ls1 += cv0 + cv1;
      ls2 += cv0 * cv0 + cv1 * cv1;
    }
  }
#pragma unroll
  for (int off = 32; off >= 1; off >>= 1) {
    ls1 += __shfl_down(ls1, off);
    ls2 += __shfl_down(ls2, off);
    ts1 += __shfl_down(ts1, off);
    ts2 += __shfl_down(ts2, off);
  }
  if (lane == 0) { swd1[w] = ls1; swd2[w] = ls2; swv1[w] = ts1; swv2[w] = ts2; }
  __syncthreads();
  if (tid == 0) {
    float d1 = 0.0f, d2 = 0.0f, v1 = 0.0f, v2 = 0.0f;
#pragma unroll
    for (int i = 0; i < 8; ++i) { d1 += swd1[i]; d2 += swd2[i]; v1 += swv1[i]; v2 += swv2[i]; }
    part[192 + (bh * 4 + jq) * 2 + 0] = d1;
    part[192 + (bh * 4 + jq) * 2 + 1] = d2;
    if (jq == 0) { part[bh * 2] = v1; part[bh * 2 + 1] = v2; }
  }
}

// ---------------- K45: stats + bn+leaky+mask + ZERO-BARRIER row softmax + AV ----------------
// Thread tid owns row tid>>4, cols (tid&15)*16..+15: cv as 4x float4 (256B/16-lane group),
// row softmax entirely via 16-lane shfl_xor (no smax/ssum LDS, 2 fewer barriers).
__global__ __launch_bounds__(256) void k45_fused(const float* __restrict__ cvws,
    const unsigned short* __restrict__ xT, const int* __restrict__ tids,
    const float* __restrict__ part, unsigned short* __restrict__ vc16) {
  int bid = blockIdx.x;
  int xcd = bid & 7, idx = bid >> 3;
  int bh = xcd * 12 + idx % 12;            // 96 bh / 8 XCDs = 12 each
  int p = idx / 12;
  int b = bh / 6, h = bh % 6;
  int tid = threadIdx.x, w = tid >> 6, lane = tid & 63;
  int quad = lane >> 4, l16 = lane & 15;
  int I = p * 16;
  __shared__ unsigned short cot[16][264];  // co tile; reused as vc restage buffer (vt)
  __shared__ float sstat[4];               // m, rsc, mv, rvs
  int row = tid >> 4, cg = tid & 15;
  // issue independent loads before the stats barrier (latency hidden under it)
  const float* cvr = cvws + ((size_t)bh * 256 + I + row) * 256 + cg * 16;
  f32x4 v0 = *(const f32x4*)(cvr + 0);
  f32x4 v1 = *(const f32x4*)(cvr + 4);
  f32x4 v2 = *(const f32x4*)(cvr + 8);
  f32x4 v3 = *(const f32x4*)(cvr + 12);
  const int4* tco = (const int4*)(tids + b * 256 + cg * 16);
  int4 t0 = tco[0], t1 = tco[1], t2 = tco[2], t3 = tco[3];
  float rvr = (tids[b * 256 + I + row] != 0) ? 1.0f : 0.0f;
  if (w == 0) {                            // finalize BN stats from k12 partials (this h only)
    float c1 = 0.0f, c2 = 0.0f;
    {
      int bb = lane >> 2, jj = lane & 3;   // 16 b x 4 jq = 64 lanes
      c1 = part[192 + ((bb * 6 + h) * 4 + jj) * 2 + 0];
      c2 = part[192 + ((bb * 6 + h) * 4 + jj) * 2 + 1];
    }
    float vv1 = 0.0f, vv2 = 0.0f;
    if (lane < 16) {
      vv1 = part[(lane * 6 + h) * 2 + 0];
      vv2 = part[(lane * 6 + h) * 2 + 1];
    }
#pragma unroll
    for (int off = 32; off >= 1; off >>= 1) {
      c1 += __shfl_down(c1, off);
      c2 += __shfl_down(c2, off);
      vv1 += __shfl_down(vv1, off);
      vv2 += __shfl_down(vv2, off);
    }
    if (lane == 0) {
      float mean = c1 / 1048576.0f;                    // B*L*L
      float var = c2 / 1048576.0f - mean * mean;
      sstat[0] = mean;
      sstat[1] = rsqrtf(var + 1e-5f);
      float mv = vv1 / 524288.0f;                      // B*L*dh
      float vv = vv2 / 524288.0f - mv * mv;
      sstat[2] = mv;
      sstat[3] = rsqrtf(vv + 1e-5f);
    }
  }
  __syncthreads();
  float m = sstat[0], rsc = sstat[1];
  float cvl[16];
  cvl[0] = t0.x ? 1.0f : 0.0f;  cvl[1] = t0.y ? 1.0f : 0.0f;
  cvl[2] = t0.z ? 1.0f : 0.0f;  cvl[3] = t0.w ? 1.0f : 0.0f;
  cvl[4] = t1.x ? 1.0f : 0.0f;  cvl[5] = t1.y ? 1.0f : 0.0f;
  cvl[6] = t1.z ? 1.0f : 0.0f;  cvl[7] = t1.w ? 1.0f : 0.0f;
  cvl[8] = t2.x ? 1.0f : 0.0f;  cvl[9] = t2.y ? 1.0f : 0.0f;
  cvl[10] = t2.z ? 1.0f : 0.0f; cvl[11] = t2.w ? 1.0f : 0.0f;
  cvl[12] = t3.x ? 1.0f : 0.0f; cvl[13] = t3.y ? 1.0f : 0.0f;
  cvl[14] = t3.z ? 1.0f : 0.0f; cvl[15] = t3.w ? 1.0f : 0.0f;
  float y[16];
#pragma unroll
  for (int e = 0; e < 16; ++e) {
    float cv = (e < 4) ? v0[e] : (e < 8) ? v1[e - 4] : (e < 12) ? v2[e - 8] : v3[e - 12];
    float yv = (cv - m) * rsc;
    yv = yv >= 0.0f ? yv : 9.0f * yv;
    y[e] = yv * rvr * cvl[e];
  }
  float mx = y[0];
#pragma unroll
  for (int e = 1; e < 16; ++e) mx = fmaxf(mx, y[e]);
#pragma unroll
  for (int off = 1; off <= 8; off <<= 1) mx = fmaxf(mx, __shfl_xor(mx, off));
  float s = 0.0f;
#pragma unroll
  for (int e = 0; e < 16; ++e) { y[e] = expf(y[e] - mx); s += y[e]; }
#pragma unroll
  for (int off = 1; off <= 8; off <<= 1) s += __shfl_xor(s, off);
  float inv = 1.0f / s;
  u16x8 o0, o1;
#pragma unroll
  for (int e = 0; e < 8; ++e) {
    o0[e] = __bfloat16_as_ushort(__float2bfloat16(y[e] * inv));
    o1[e] = __bfloat16_as_ushort(__float2bfloat16(y[8 + e] * inv));
  }
  *(u16x8*)&cot[row][cg * 16] = o0;
  *(u16x8*)&cot[row][cg * 16 + 8] = o1;
  __syncthreads();
  bf16x8 a2[8];
#pragma unroll
  for (int k0 = 0; k0 < 8; ++k0)
    a2[k0] = *(const bf16x8*)&cot[l16][k0 * 32 + quad * 8];
  __syncthreads();                         // cot fragments now in regs; reuse cot as vt
  const __bf16* xbT = (const __bf16*)xT + (size_t)bh * 128 * 256;
  float mv = sstat[2], rvs = sstat[3];
  float rm = rvs * mv;
#pragma unroll
  for (int jl = 0; jl < 2; ++jl) {
    int ch = (w * 2 + jl) * 16 + l16;
    const __bf16* brow = xbT + (size_t)ch * 256;
    f32x4 vacc = {0.0f, 0.0f, 0.0f, 0.0f};
#pragma unroll
    for (int k0 = 0; k0 < 8; ++k0) {
      bf16x8 bfr = *(const bf16x8*)(brow + k0 * 32 + quad * 8);
      vacc = __builtin_amdgcn_mfma_f32_16x16x32_bf16(a2[k0], bfr, vacc, 0, 0, 0);
    }
#pragma unroll
    for (int r = 0; r < 4; ++r) {
      float ov = rvs * vacc[r] - rm;
      cot[quad * 4 + r][ch] = __bfloat16_as_ushort(__float2bfloat16(ov));   // vt stage
    }
  }
  __syncthreads();
  {                                        // coalesced vc store: 1 u16x8 per thread
    int rw = tid >> 4, seg = (tid & 15) * 8;
    u16x8 pkv = *(const u16x8*)&cot[rw][seg];
    *(u16x8*)(vc16 + ((size_t)(b * 256 + I + rw)) * 768 + h * 128 + seg) = pkv;
  }
}

// ---------------- K5b6: logits via MFMA + 21-softmax + accumulate + last-block final softmax ----------------
// (identical to R12/R9)
__global__ __launch_bounds__(256) void k5b6_lgts(const unsigned short* __restrict__ vc16,
    const unsigned short* __restrict__ fcWb, const float* __restrict__ fcb,
    float* __restrict__ acc, unsigned int* __restrict__ ctr, float* __restrict__ out) {
  int bid = blockIdx.x;
  int xcd = bid & 7, idx = bid >> 3;       // 8 blocks per XCD
  int b = xcd * 2 + (idx & 1);             // matches k45's b->XCD map
  int qa = idx >> 1;
  int tid = threadIdx.x, w = tid >> 6, lane = tid & 63;
  int quad = lane >> 4, l16 = lane & 15;
  int tok0 = b * 256 + qa * 64 + w * 16;
  int c1c = (l16 < 5) ? (16 + l16) : 20;
  const __bf16* vb = (const __bf16*)vc16;
  const __bf16* w0 = (const __bf16*)fcWb + (size_t)l16 * 768;
  const __bf16* w1 = (const __bf16*)fcWb + (size_t)c1c * 768;
  f32x4 ac0 = {0.0f, 0.0f, 0.0f, 0.0f}, ac1 = {0.0f, 0.0f, 0.0f, 0.0f};
#pragma unroll
  for (int k0 = 0; k0 < 24; ++k0) {
    int ko = k0 * 32 + quad * 8;
    bf16x8 af = *(const bf16x8*)(vb + (size_t)(tok0 + l16) * 768 + ko);
    bf16x8 b0 = *(const bf16x8*)(w0 + ko);
    bf16x8 b1 = *(const bf16x8*)(w1 + ko);
    ac0 = __builtin_amdgcn_mfma_f32_16x16x32_bf16(af, b0, ac0, 0, 0, 0);
    ac1 = __builtin_amdgcn_mfma_f32_16x16x32_bf16(af, b1, ac1, 0, 0, 0);
  }
  float bias0 = fcb[l16];
  float bias1 = (l16 < 5) ? fcb[16 + l16] : 0.0f;
  float p0s = 0.0f, p1s = 0.0f;
#pragma unroll
  for (int r = 0; r < 4; ++r) {
    float lg0 = ac0[r] + bias0;
    float lg1 = (l16 < 5) ? (ac1[r] + bias1) : -1e30f;
    float mx = fmaxf(lg0, lg1);
#pragma unroll
    for (int off = 1; off <= 8; off <<= 1) mx = fmaxf(mx, __shfl_xor(mx, off));
    float e0 = expf(lg0 - mx), e1 = expf(lg1 - mx);
    float s = e0 + e1;
#pragma unroll
    for (int off = 1; off <= 8; off <<= 1) s += __shfl_xor(s, off);
    float inv = 1.0f / s;
    p0s += e0 * inv;
    p1s += e1 * inv;
  }
  p0s += __shfl_xor(p0s, 16); p0s += __shfl_xor(p0s, 32);
  p1s += __shfl_xor(p1s, 16); p1s += __shfl_xor(p1s, 32);
  __shared__ float sacc[4][21];
  __shared__ unsigned int sdone;
  if (quad == 0) sacc[w][l16] = p0s;
  if (quad == 1 && l16 < 5) sacc[w][16 + l16] = p1s;
  __syncthreads();
  if (tid < 21) {
    float s = sacc[0][tid] + sacc[1][tid] + sacc[2][tid] + sacc[3][tid];
    atomicAdd(&acc[b * 21 + tid], s);
  }
  __syncthreads();   // barrier drains vmcnt: this block's atomics are globally performed
  if (tid == 0) {
    __threadfence();
    sdone = atomicAdd(ctr, 1u);
  }
  __syncthreads();
  if (sdone == 63u && tid < 16) {
    float v[20];
    float mx = -1e30f;
#pragma unroll
    for (int c = 0; c < 20; ++c) {
      v[c] = atomicAdd(&acc[tid * 21 + c], 0.0f);   // coherent read (XCD-safe)
      mx = fmaxf(mx, v[c]);
    }
    float s = 0.0f;
#pragma unroll
    for (int c = 0; c < 20; ++c) { v[c] = expf(v[c] - mx); s += v[c]; }
    float inv = 1.0f / s;
#pragma unroll
    for (int c = 0; c < 20; ++c) out[tid * 20 + c] = v[c] * inv;
  }
}

extern "C" void kernel_launch(void* const* d_in, const int* in_sizes, int n_in,
                              void* d_out, int out_size, void* d_ws, size_t ws_size,
                              hipStream_t stream) {
  const int*   tids = (const int*)d_in[0];
  const float* TF   = (const float*)d_in[1];
  const float* DF   = (const float*)d_in[2];
  const float* emb  = (const float*)d_in[3];
  const float* fcW  = (const float*)d_in[4];
  const float* fcb  = (const float*)d_in[5];
  // d_in[6]=weiW, d_in[7]=weib: dead code (cw branch is provably all-ones)
  float* out = (float*)d_out;
  float* ws  = (float*)d_ws;
  unsigned short* xT   = (unsigned short*)(ws + OFF_XT);
  unsigned short* vc   = (unsigned short*)(ws + OFF_VC);
  unsigned short* fcWb = (unsigned short*)(ws + OFF_FCWB);
  float* part  = ws + OFF_PART;
  float* acc   = ws + OFF_ACC;
  float* cvws  = ws + OFF_CV;
  unsigned int* ctr = (unsigned int*)(ws + OFF_CTR);

  k12_fused<<<384, 512, 0, stream>>>(tids, TF, DF, emb, xT, part,
                                     fcW, fcWb, acc, ctr, cvws);
  k45_fused<<<1536, 256, 0, stream>>>(cvws, xT, tids, part, vc);
  k5b6_lgts<<<64, 256, 0, stream>>>(vc, fcWb, fcb, acc, ctr, out);
}